// Round 2
// 269.516 us; speedup vs baseline: 1.0491x; 1.0491x over previous
//
#include <hip/hip_runtime.h>

// Shapes (fixed by setup_inputs): N=1, L1=256, K=128, L2=1024,
// c_s=384, c_m=256, ch=32, c_z=128
#define L1V 256
#define L2V 1024
#define KV  128
#define CSV 384
#define CMV 256
#define CHV 32
#define CZV 128

// Native vector types for __builtin_nontemporal_* (HIP float4/float2 are
// classes, which the builtin rejects).
typedef float f4v __attribute__((ext_vector_type(4)));
typedef float f2v __attribute__((ext_vector_type(2)));

__device__ __forceinline__ float4 f4zero() { return make_float4(0.f,0.f,0.f,0.f); }

__device__ __forceinline__ float4 nt_load4(const float4* p) {
  f4v t = __builtin_nontemporal_load((const f4v*)p);
  return make_float4(t.x, t.y, t.z, t.w);
}

// Per-row LN stats (full-wave reduction over 256 elems = 64 lanes x float4),
// then accumulate normalized row into xs.
__device__ __forceinline__ void ln_accum(const float4 x, float4& xs) {
  float s1 = x.x + x.y + x.z + x.w;
  float s2 = fmaf(x.x, x.x, fmaf(x.y, x.y, fmaf(x.z, x.z, x.w * x.w)));
  #pragma unroll
  for (int off = 32; off > 0; off >>= 1) {
    s1 += __shfl_xor(s1, off, 64);
    s2 += __shfl_xor(s2, off, 64);
  }
  const float mu   = s1 * (1.0f / CMV);
  const float rstd = rsqrtf(s2 * (1.0f / CMV) - mu * mu + 1e-5f);
  xs.x = fmaf(x.x - mu, rstd, xs.x);
  xs.y = fmaf(x.y - mu, rstd, xs.y);
  xs.z = fmaf(x.z - mu, rstd, xs.z);
  xs.w = fmaf(x.w - mu, rstd, xs.w);
}

// ---------------------------------------------------------------------------
// Kernel A: m_sum[j,c] = sum_k (LN(m[k,j,:]) * g + b) @ W_ag + K*b_ag
// K-sum commutes inside the projection -> accumulate xhat, project once per j.
// grid = 1024 (block per j), block = 256; ~134 MB streamed, HBM-floor ~21 us.
// R3: nontemporal loads for the read-once m stream (don't cycle L2).
// ---------------------------------------------------------------------------
__global__ __launch_bounds__(256) void msum_kernel(
    const float* __restrict__ m, const float* __restrict__ g,
    const float* __restrict__ b, const float* __restrict__ Wag,
    const float* __restrict__ bag, float* __restrict__ msum)
{
  const int j    = blockIdx.x;
  const int tid  = threadIdx.x;
  const int wave = tid >> 6;
  const int lane = tid & 63;

  const float4* base = (const float4*)m;  // row k at float4 index (k*1024+j)*64

  float4 xs = f4zero();
  float4 x0 = nt_load4(&base[(((size_t)wave << 10) + j) * 64 + lane]);
  float4 x1 = nt_load4(&base[(((size_t)(wave + 4) << 10) + j) * 64 + lane]);

  for (int k = wave; k < KV; k += 8) {
    float4 n0 = f4zero(), n1 = f4zero();
    if (k + 8  < KV) n0 = nt_load4(&base[(((size_t)(k + 8)  << 10) + j) * 64 + lane]);
    if (k + 12 < KV) n1 = nt_load4(&base[(((size_t)(k + 12) << 10) + j) * 64 + lane]);
    ln_accum(x0, xs);
    ln_accum(x1, xs);
    x0 = n0; x1 = n1;
  }

  __shared__ float xsum[4][CMV];
  ((float4*)xsum[wave])[lane] = xs;
  __syncthreads();

  // y[e] = xhat_sum[e]*g[e] + K*b[e]  (folds LN affine + K-sum of bias)
  __shared__ float y[CMV];
  y[tid] = (xsum[0][tid] + xsum[1][tid] + xsum[2][tid] + xsum[3][tid]) * g[tid]
           + (float)KV * b[tid];
  __syncthreads();

  // projection: thread t handles c = t&31, e-chunk = t>>5 (8 chunks of 32)
  const int c     = tid & 31;
  const int chunk = tid >> 5;
  float p = 0.f;
  #pragma unroll
  for (int q = 0; q < 32; ++q) {
    const int e = (chunk << 5) + q;
    p = fmaf(y[e], Wag[(e << 5) + c], p);
  }
  __shared__ float pr[256];
  pr[tid] = p;
  __syncthreads();
  if (tid < 32) {
    float acc = 0.f;
    #pragma unroll
    for (int r = 0; r < 8; ++r) acc += pr[tid + (r << 5)];
    msum[(j << 5) + tid] = acc + (float)KV * bag[tid];
  }
}

// ---------------------------------------------------------------------------
// Kernel B1: a[i,c] = (LN(s[i,:])*g + b) @ W_ab + b_ab
// grid = 256 (block per row i), block = 384 (one thread per element)
// ---------------------------------------------------------------------------
__global__ __launch_bounds__(384) void a_kernel(
    const float* __restrict__ s, const float* __restrict__ g,
    const float* __restrict__ b, const float* __restrict__ Wab,
    const float* __restrict__ bab, float* __restrict__ a)
{
  const int i    = blockIdx.x;
  const int tid  = threadIdx.x;
  const int wave = tid >> 6;   // 0..5
  const int lane = tid & 63;

  const float x = s[i * CSV + tid];
  float s1 = x, s2 = x * x;
  #pragma unroll
  for (int off = 32; off > 0; off >>= 1) {
    s1 += __shfl_xor(s1, off, 64);
    s2 += __shfl_xor(s2, off, 64);
  }
  __shared__ float r1[6], r2[6];
  if (lane == 0) { r1[wave] = s1; r2[wave] = s2; }
  __syncthreads();
  float t1 = 0.f, t2 = 0.f;
  #pragma unroll
  for (int w = 0; w < 6; ++w) { t1 += r1[w]; t2 += r2[w]; }
  const float mu   = t1 * (1.0f / CSV);
  const float rstd = rsqrtf(t2 * (1.0f / CSV) - mu * mu + 1e-5f);

  __shared__ float y[CSV];
  y[tid] = (x - mu) * rstd * g[tid] + b[tid];
  __syncthreads();

  const int c     = tid & 31;
  const int chunk = tid >> 5;  // 0..11
  float p = 0.f;
  #pragma unroll
  for (int q = 0; q < 32; ++q) {
    const int e = (chunk << 5) + q;
    p = fmaf(y[e], Wab[(e << 5) + c], p);
  }
  __shared__ float pr[CSV];
  pr[tid] = p;
  __syncthreads();
  if (tid < 32) {
    float acc = 0.f;
    #pragma unroll
    for (int r = 0; r < 12; ++r) acc += pr[tid + (r << 5)];
    a[(i << 5) + tid] = acc + bab[tid];
  }
}

// ---------------------------------------------------------------------------
// Kernel B2: T[i,idx] = sum_c a[i,c] * W_out[c*4096 + idx], idx = e*128+z
// grid = (16 idx-chunks, 16 i-chunks) = 256 blocks. a-tile in LDS
// (broadcast), W_out column in 32 VGPRs.
// ---------------------------------------------------------------------------
__global__ __launch_bounds__(256) void t_kernel(
    const float* __restrict__ a, const float* __restrict__ Wout,
    float* __restrict__ T)
{
  const int tid = threadIdx.x;
  const int idx = (blockIdx.x << 8) + tid;   // 0..4095
  const int i0  = blockIdx.y << 4;           // 0,16,...,240

  __shared__ float as[16 * 32];
  #pragma unroll
  for (int r = 0; r < 2; ++r) {
    const int t = (r << 8) + tid;
    as[t] = a[(i0 << 5) + t];
  }
  __syncthreads();

  float w[32];
  #pragma unroll
  for (int c = 0; c < 32; ++c) w[c] = Wout[(c << 12) + idx];

  #pragma unroll 4
  for (int ii = 0; ii < 16; ++ii) {
    float acc = 0.f;
    #pragma unroll
    for (int c = 0; c < 32; ++c)
      acc = fmaf(as[(ii << 5) + c], w[c], acc);
    T[((size_t)(i0 + ii) << 12) + idx] = acc;
  }
}

// ---------------------------------------------------------------------------
// Kernel C (R3 REWRITE): out[i,j,z] = (m_sum[j,:] @ T[i][:,z] + b_out[z]) / norm
// Old version pushed 2 MB/block through the LDS pipe (512 ds_read_b128 per
// thread, 16 barriers) just to broadcast 128-B msum rows -> ~20 us of DS time
// serialized against the store stream at 2 waves/SIMD occupancy.
// New structure: j is WAVE-UNIFORM (each wave owns a contiguous 128-j strip):
//   - T[i, e, z-pair] lives in 64 VGPRs (float2 per lane), inv_norm pre-folded
//   - msum[j,:] read via uniform-address loads (wave-uniform base -> scalar
//     or L1-broadcast path), hand-pipelined 2 rows deep
//   - ZERO LDS, ZERO barriers; nontemporal float2 stores (134 MB stream,
//     never re-read -> keep L2 hot for T/msum)
// Per j per wave: 8 uniform loads + 64 fma (128 issue cyc) + one 512-B store
// -> store demand >> 6.9 TB/s achievable => purely store-bound, ~22 us.
// ---------------------------------------------------------------------------
__global__ __launch_bounds__(256) void out_kernel(
    const float* __restrict__ msum, const float* __restrict__ T,
    const float* __restrict__ bout, float* __restrict__ out)
{
  const int half = blockIdx.x;   // 0..1 (j halves)
  const int i    = blockIdx.y;   // 0..255
  const int wid  = __builtin_amdgcn_readfirstlane((int)(threadIdx.x >> 6)); // 0..3
  const int lane = threadIdx.x & 63;
  const int z0   = lane << 1;    // z pair start: 0,2,...,126

  const float inv_norm = 1.0f / ((float)KV + 1e-3f);

  // T[i, e, z0:z0+2] for all 32 e, pre-scaled by inv_norm (folds the /norm)
  float2 Tr[32];
  #pragma unroll
  for (int e = 0; e < 32; ++e) {
    const float2 t = *(const float2*)(T + ((size_t)i << 12) + (e << 7) + z0);
    Tr[e] = make_float2(t.x * inv_norm, t.y * inv_norm);
  }
  float2 bz = *(const float2*)(bout + z0);
  bz.x *= inv_norm; bz.y *= inv_norm;

  const int j0 = (half << 9) + (wid << 7);   // wave's j base; 128 consecutive j
  float* const outp = out + ((size_t)i << 17);

  float4 mA[8], mB[8];

#define LOADROW(BUF, J) do {                                                \
    const float4* mr = (const float4*)(msum + ((size_t)(J) << 5));          \
    _Pragma("unroll")                                                       \
    for (int q = 0; q < 8; ++q) BUF[q] = mr[q];                             \
  } while (0)

#define FMA_STORE(BUF, J) do {                                              \
    float ax = bz.x, ay = bz.y;                                             \
    _Pragma("unroll")                                                       \
    for (int q = 0; q < 8; ++q) {                                           \
      const float4 mq = BUF[q];                                             \
      ax = fmaf(mq.x, Tr[(q<<2)+0].x, ax); ay = fmaf(mq.x, Tr[(q<<2)+0].y, ay); \
      ax = fmaf(mq.y, Tr[(q<<2)+1].x, ax); ay = fmaf(mq.y, Tr[(q<<2)+1].y, ay); \
      ax = fmaf(mq.z, Tr[(q<<2)+2].x, ax); ay = fmaf(mq.z, Tr[(q<<2)+2].y, ay); \
      ax = fmaf(mq.w, Tr[(q<<2)+3].x, ax); ay = fmaf(mq.w, Tr[(q<<2)+3].y, ay); \
    }                                                                       \
    f2v ov; ov.x = ax; ov.y = ay;                                           \
    __builtin_nontemporal_store(ov,                                         \
        (f2v*)(outp + ((size_t)(J) << 7) + z0));                            \
  } while (0)

  LOADROW(mA, j0);
  for (int jj = 0; jj < 128; jj += 2) {
    LOADROW(mB, j0 + jj + 1);
    FMA_STORE(mA, j0 + jj);
    if (jj + 2 < 128) LOADROW(mA, j0 + jj + 2);
    FMA_STORE(mB, j0 + jj + 1);
  }
#undef LOADROW
#undef FMA_STORE
}

// ---------------------------------------------------------------------------
extern "C" void kernel_launch(void* const* d_in, const int* in_sizes, int n_in,
                              void* d_out, int out_size, void* d_ws, size_t ws_size,
                              hipStream_t stream) {
  (void)in_sizes; (void)n_in; (void)out_size; (void)ws_size;
  const float* s    = (const float*)d_in[0];
  const float* m    = (const float*)d_in[1];
  const float* g_ab = (const float*)d_in[2];
  const float* b_ab = (const float*)d_in[3];
  const float* g_ag = (const float*)d_in[4];
  const float* b_ag = (const float*)d_in[5];
  const float* Wab  = (const float*)d_in[6];
  const float* bab  = (const float*)d_in[7];
  const float* Wag  = (const float*)d_in[8];
  const float* bag  = (const float*)d_in[9];
  const float* Wout = (const float*)d_in[10];
  const float* bout = (const float*)d_in[11];
  float* out = (float*)d_out;

  // workspace layout (fp32): msum[1024*32] | a[256*32] | T[256*32*128]
  float* msum = (float*)d_ws;
  float* a    = msum + 32768;
  float* T    = a + 8192;   // 4 MB

  hipLaunchKernelGGL(msum_kernel, dim3(1024), dim3(256), 0, stream,
                     m, g_ag, b_ag, Wag, bag, msum);
  hipLaunchKernelGGL(a_kernel, dim3(256), dim3(384), 0, stream,
                     s, g_ab, b_ab, Wab, bab, a);
  hipLaunchKernelGGL(t_kernel, dim3(16, 16), dim3(256), 0, stream,
                     a, Wout, T);
  hipLaunchKernelGGL(out_kernel, dim3(2, 256), dim3(256), 0, stream,
                     msum, T, bout, out);
}